// Round 8
// baseline (255.294 us; speedup 1.0000x reference)
//
#include <hip/hip_runtime.h>

// QuantizerEncoder: code[n,h,w,m] = argmax_k < wq[m] @ q_raw[n,h,w,m], wk[m] @ cb[m,k] >
// n=16, d=512, h=64, w=64, m=4, kcodes=256, dm=128
//
// Round 13: argmax depth-2 load pipeline (T14/T3). R12 structure kept (1 barrier/row,
// parallel 8-way merge, amortized rescue). Change: row loop unrolled x2 with static
// pfA/pfB ping-pong (rule #20). Loads for row r+2 issue at top of row r (2 bodies of
// slack; register loads stay in flight across barriers -- no vmcnt drain for reg
// destinations). Convert of row r+1 moves to the TOP of row r+1 (off the pre-barrier
// critical path, overlaps first tile's lgkm waits), held as 2 f16x8 until the
// post-compute LDS write. Reg audit: persistent Af32+pfA16+pfB16+cv4+bases~14 = 82,
// peak ~116 < 128 cap of (512,4) -- R8 spill lesson respected.

#define MM   4
#define KC   256
#define DM   128
#define HW   4096   // h*w
#define WW_  64
#define EPS  0.045f
#define WLC  16384  // per-m worklist capacity
#define RPB  4      // pixels per rescue sweep
#define RSH  136    // LDS row stride in halfs (272B, 16B-aligned, conflict-free b128)

typedef _Float16 f16x8 __attribute__((ext_vector_type(8)));
typedef _Float16 f16x4 __attribute__((ext_vector_type(4)));
typedef _Float16 f16x2 __attribute__((ext_vector_type(2)));
typedef float    f32x4 __attribute__((ext_vector_type(4)));
typedef float    f32x2 __attribute__((ext_vector_type(2)));

// ---- Kernel 1: A[m][e][d] = sum_c wk[m][c][e] * wq[m][c][d]  (fp64) ----
__global__ __launch_bounds__(128) void a_kernel(const float* __restrict__ wk,
                                                const float* __restrict__ wq,
                                                double* __restrict__ A) {
    int me = blockIdx.x;           // m*128 + e
    int d  = threadIdx.x;
    int m  = me >> 7;
    int e  = me & 127;
    const float* wkm = wk + (size_t)m * DM * DM + e;       // wk[m][c][e], stride DM
    const float* wqm = wq + (size_t)m * DM * DM + d;       // wq[m][c][d], stride DM
    double s0 = 0.0, s1 = 0.0, s2 = 0.0, s3 = 0.0;
#pragma unroll 8
    for (int c = 0; c < DM; c += 4) {
        s0 = fma((double)wkm[(size_t)(c+0) * DM], (double)wqm[(size_t)(c+0) * DM], s0);
        s1 = fma((double)wkm[(size_t)(c+1) * DM], (double)wqm[(size_t)(c+1) * DM], s1);
        s2 = fma((double)wkm[(size_t)(c+2) * DM], (double)wqm[(size_t)(c+2) * DM], s2);
        s3 = fma((double)wkm[(size_t)(c+3) * DM], (double)wqm[(size_t)(c+3) * DM], s3);
    }
    A[(size_t)me * DM + d] = (s0 + s1) + (s2 + s3);
}

// ---- Kernel 2: keff[m][k][d] = sum_e cb[m][k][e]*A[m][e][d]; store fp16 + fp64-transposed ----
__global__ __launch_bounds__(128) void keff_kernel(const float* __restrict__ cb,
                                                   const double* __restrict__ A,
                                                   double* __restrict__ keffdT,
                                                   _Float16* __restrict__ keff16) {
    int mk = blockIdx.x;           // m*256 + k
    int d  = threadIdx.x;
    int m  = mk >> 8;
    int k  = mk & 255;
    const float*  cbr = cb + (size_t)mk * DM;              // cb[m][k][*]
    const double* Am  = A + (size_t)m * DM * DM + d;       // A[m][e][d], stride DM
    double s0 = 0.0, s1 = 0.0, s2 = 0.0, s3 = 0.0;
#pragma unroll 8
    for (int e = 0; e < DM; e += 4) {
        s0 = fma((double)cbr[e+0], Am[(size_t)(e+0) * DM], s0);
        s1 = fma((double)cbr[e+1], Am[(size_t)(e+1) * DM], s1);
        s2 = fma((double)cbr[e+2], Am[(size_t)(e+2) * DM], s2);
        s3 = fma((double)cbr[e+3], Am[(size_t)(e+3) * DM], s3);
    }
    double s = (s0 + s1) + (s2 + s3);
    keffdT[((size_t)m * DM + d) * KC + k] = s;             // transposed: rescue reads coalesced
    keff16[(size_t)mk * DM + d] = (_Float16)s;
}

// ---- Kernel 3: MFMA argmax, 8 waves x 32 codes, 8 rows/block, 512 blocks ----
// Row body as macro: CUR is the lq/partials buffer (compile-time-ish), PFC holds row
// R+1's raw loads (converted here), PFN receives row R+2's loads (issued here).
#define ARG_BODY(R, CUR, PFC, PFN)                                                \
  do {                                                                            \
    f16x8 cv0, cv1;                                                               \
    if ((R) < 7) {                                                                \
      _Pragma("unroll")                                                           \
      for (int pp = 0; pp < 8; ++pp) { cv0[pp] = (_Float16)PFC[pp][0];            \
                                       cv1[pp] = (_Float16)PFC[pp][1]; }          \
    }                                                                             \
    if ((R) < 6) {                                                                \
      const float* lp_ = lp0 + (size_t)((R) + 2) * WW_;                           \
      _Pragma("unroll")                                                           \
      for (int pp = 0; pp < 8; ++pp)                                              \
        PFN[pp] = *(const f32x2*)(lp_ + (size_t)(db + pp) * HW + w2);             \
    }                                                                             \
    _Pragma("unroll")                                                             \
    for (int p = 0; p < 4; ++p) {                                                 \
      f16x8 Bf[4];                                                                \
      _Pragma("unroll")                                                           \
      for (int s = 0; s < 4; ++s)                                                 \
        Bf[s] = *(const f16x8*)&lq[CUR][(size_t)(p * 16 + col) * RSH + s * 32 + quad * 8]; \
      f32x4 acc[2];                                                               \
      _Pragma("unroll")                                                           \
      for (int t = 0; t < 2; ++t) {                                               \
        f32x4 c_ = (f32x4){0.f, 0.f, 0.f, 0.f};                                   \
        c_ = __builtin_amdgcn_mfma_f32_16x16x32_f16(Af[t][0], Bf[0], c_, 0, 0, 0);\
        c_ = __builtin_amdgcn_mfma_f32_16x16x32_f16(Af[t][1], Bf[1], c_, 0, 0, 0);\
        c_ = __builtin_amdgcn_mfma_f32_16x16x32_f16(Af[t][2], Bf[2], c_, 0, 0, 0);\
        c_ = __builtin_amdgcn_mfma_f32_16x16x32_f16(Af[t][3], Bf[3], c_, 0, 0, 0);\
        acc[t] = c_;                                                              \
      }                                                                           \
      float bv = acc[0][0];                                                       \
      int   bi = wave * 32 + quad * 4;                                            \
      float sv = -3.0e38f;                                                        \
      _Pragma("unroll")                                                           \
      for (int t = 0; t < 2; ++t)                                                 \
        _Pragma("unroll")                                                         \
        for (int g = 0; g < 4; ++g) {                                             \
          if (t == 0 && g == 0) continue;                                         \
          float v_   = acc[t][g];                                                 \
          int   idx_ = wave * 32 + t * 16 + quad * 4 + g;                         \
          if (v_ > bv)      { sv = bv; bv = v_; bi = idx_; }                      \
          else if (v_ > sv) sv = v_;                                              \
        }                                                                         \
      _Pragma("unroll")                                                           \
      for (int off = 16; off < 64; off <<= 1) {                                   \
        float ov = __shfl_xor(bv, off);                                           \
        int   oi = __shfl_xor(bi, off);                                           \
        float os = __shfl_xor(sv, off);                                           \
        bool  take  = (ov > bv) || (ov == bv && oi < bi);                         \
        float loser = take ? bv : ov;                                             \
        sv = fmaxf(fmaxf(sv, os), loser);                                         \
        if (take) { bv = ov; bi = oi; }                                           \
      }                                                                           \
      if (quad == 0) {                                                            \
        int P_ = p * 16 + col;                                                    \
        pbv[CUR][P_][wave] = bv; psv[CUR][P_][wave] = sv; pbi[CUR][P_][wave] = bi;\
      }                                                                           \
    }                                                                             \
    if ((R) < 7) {                                                                \
      *(f16x8*)&lq[(CUR) ^ 1][(size_t)(w2 + 0) * RSH + db] = cv0;                 \
      *(f16x8*)&lq[(CUR) ^ 1][(size_t)(w2 + 1) * RSH + db] = cv1;                 \
    }                                                                             \
    __syncthreads();                                                              \
    {                                                                             \
      int P_    = tid >> 3;                                                       \
      int slot_ = tid & 7;                                                        \
      float bv = pbv[CUR][P_][slot_];                                             \
      float sv = psv[CUR][P_][slot_];                                             \
      int   bi = pbi[CUR][P_][slot_];                                             \
      _Pragma("unroll")                                                           \
      for (int off = 1; off < 8; off <<= 1) {                                     \
        float ov = __shfl_xor(bv, off);                                           \
        int   oi = __shfl_xor(bi, off);                                           \
        float os = __shfl_xor(sv, off);                                           \
        bool  take  = (ov > bv) || (ov == bv && oi < bi);                         \
        float loser = take ? bv : ov;                                             \
        sv = fmaxf(fmaxf(sv, os), loser);                                         \
        if (take) { bv = ov; bi = oi; }                                           \
      }                                                                           \
      if (slot_ == 0) {                                                           \
        int h_   = hg * 8 + (R);                                                  \
        int pix_ = (((n * 64 + h_) * 64) + P_) * MM + m;                          \
        out[pix_] = bi;                                                           \
        if (bv - sv < EPS) {                                                      \
          int s_ = atomicAdd(wl_cnt + m * 16, 1);                                 \
          if (s_ < WLC) wl[m * WLC + s_] = pix_;                                  \
        }                                                                         \
      }                                                                           \
    }                                                                             \
  } while (0)

__global__ __launch_bounds__(512, 4) void argmax_mfma(const float* __restrict__ latent,
                                                      const _Float16* __restrict__ keff16,
                                                      int* __restrict__ out,
                                                      int* __restrict__ wl_cnt,
                                                      int* __restrict__ wl) {
    __shared__ _Float16 lq[2][64 * RSH];   // 2 x 17,408 B q tiles
    __shared__ float pbv[2][64][8];        // double-buffered partials
    __shared__ float psv[2][64][8];
    __shared__ int   pbi[2][64][8];

    int blk  = blockIdx.x;          // 0..511 = n(16) x m(4) x hg(8)
    int n    = blk >> 5;
    int m    = (blk >> 3) & 3;
    int hg   = blk & 7;
    int tid  = threadIdx.x;
    int wave = tid >> 6;            // 0..7
    int lane = tid & 63;
    int col  = lane & 15;
    int quad = lane >> 4;
    int w2   = (tid & 31) * 2;      // staging: pixel base (2 pixels/thread)
    int db   = (tid >> 5) * 8;      // staging: d-plane base (16 groups x 8 = 128)

    // ---- A-frags: this wave's 32 codes [wave*32, wave*32+32), 32 VGPRs ----
    f16x8 Af[2][4];
    {
        const _Float16* kbase = keff16 + ((size_t)m * KC + wave * 32) * DM;
#pragma unroll
        for (int t = 0; t < 2; ++t)
#pragma unroll
            for (int s = 0; s < 4; ++s)
                Af[t][s] = *(const f16x8*)(kbase + (size_t)(t * 16 + col) * DM + s * 32 + quad * 8);
    }

    const float* lp0 = latent + ((size_t)(n * 512 + m * DM)) * HW + (size_t)(hg * 8) * WW_;

    // ---- prologue: stage row 0 direct; issue row 1 loads into pfA ----
    f32x2 pfA[8], pfB[8];
    {
        f32x2 p0[8];
#pragma unroll
        for (int pp = 0; pp < 8; ++pp)
            p0[pp] = *(const f32x2*)(lp0 + (size_t)(db + pp) * HW + w2);
#pragma unroll
        for (int j = 0; j < 2; ++j) {
            f16x8 v;
#pragma unroll
            for (int pp = 0; pp < 8; ++pp) v[pp] = (_Float16)p0[pp][j];
            *(f16x8*)&lq[0][(size_t)(w2 + j) * RSH + db] = v;
        }
    }
    {
        const float* lp_ = lp0 + (size_t)1 * WW_;
#pragma unroll
        for (int pp = 0; pp < 8; ++pp)
            pfA[pp] = *(const f32x2*)(lp_ + (size_t)(db + pp) * HW + w2);
    }
    __syncthreads();

    for (int rr = 0; rr < 4; ++rr) {
        int r0 = 2 * rr;
        ARG_BODY(r0,     0, pfA, pfB);
        ARG_BODY(r0 + 1, 1, pfB, pfA);
    }
}

// ---- Kernel 4: fp64 rescue, 4 same-m pixels share one keffdT sweep ----
__global__ __launch_bounds__(256) void rescue_kernel(const float* __restrict__ latent,
                                                     const double* __restrict__ keffdT,
                                                     const int* __restrict__ wl_cnt,
                                                     const int* __restrict__ wl,
                                                     int* __restrict__ out) {
    __shared__ double sq[RPB][DM];       // 4 KB
    __shared__ double sval[256][RPB];    // 8 KB
    __shared__ int    sidx[256][RPB];    // 4 KB
    __shared__ int    spix[RPB];
    int b   = blockIdx.x;
    int m   = b & 3;
    int t   = threadIdx.x;
    int cnt = wl_cnt[m * 16];
    if (cnt > WLC) cnt = WLC;
    const int*    wlm = wl + m * WLC;
    const double* krm = keffdT + (size_t)m * DM * KC + t;   // column k=t

    for (int i0 = (b >> 2) * RPB; i0 < cnt; i0 += 256 * RPB) {
        // ---- load 4 pixels' q into LDS: 64 threads per pixel, 2 d's each ----
        int pi  = t >> 6;            // 0..3
        int dd  = (t & 63) * 2;      // 0..126
        int idx = i0 + pi;
        int vld = idx < cnt;
        int pix = wlm[vld ? idx : i0];
        int rem = pix >> 2;          // (n*64+h)*64 + w
        int w   = rem & 63;
        int bh  = rem >> 6;
        int n   = bh >> 6;
        int h   = bh & 63;
        const float* lp = latent + ((size_t)(n * 512 + m * DM)) * HW + h * WW_ + w;
        sq[pi][dd]     = (double)lp[(size_t)dd * HW];
        sq[pi][dd + 1] = (double)lp[(size_t)(dd + 1) * HW];
        if ((t & 63) == 0) spix[pi] = vld ? pix : -1;
        __syncthreads();

        // ---- one keffdT sweep, 4 dot products ----
        double s0 = 0.0, s1 = 0.0, s2 = 0.0, s3 = 0.0;
#pragma unroll 4
        for (int d = 0; d < DM; ++d) {
            double kd = krm[(size_t)d * KC];
            s0 = fma(sq[0][d], kd, s0);
            s1 = fma(sq[1][d], kd, s1);
            s2 = fma(sq[2][d], kd, s2);
            s3 = fma(sq[3][d], kd, s3);
        }
        sval[t][0] = s0; sval[t][1] = s1; sval[t][2] = s2; sval[t][3] = s3;
        sidx[t][0] = t;  sidx[t][1] = t;  sidx[t][2] = t;  sidx[t][3] = t;
        __syncthreads();

        // ---- combined tree reduction for all 4 pixels ----
        for (int stp = 128; stp > 0; stp >>= 1) {
            if (t < stp) {
#pragma unroll
                for (int p = 0; p < RPB; ++p) {
                    double vo = sval[t + stp][p], vm = sval[t][p];
                    int io = sidx[t + stp][p], im = sidx[t][p];
                    if (vo > vm || (vo == vm && io < im)) { sval[t][p] = vo; sidx[t][p] = io; }
                }
            }
            __syncthreads();
        }
        if (t < RPB) {
            int opix = spix[t];
            if (opix >= 0) out[opix] = sidx[0][t];
        }
        __syncthreads();
    }
}

extern "C" void kernel_launch(void* const* d_in, const int* in_sizes, int n_in,
                              void* d_out, int out_size, void* d_ws, size_t ws_size,
                              hipStream_t stream) {
    const float* latent = (const float*)d_in[0];   // [16,512,64,64]
    const float* cb     = (const float*)d_in[1];   // [4,256,128]
    const float* wq     = (const float*)d_in[2];   // [4,128,128]
    const float* wk     = (const float*)d_in[3];   // [4,128,128]
    int* out = (int*)d_out;                        // 262144 code indices (int32)

    // workspace layout (~2.1 MB)
    char* ws = (char*)d_ws;
    double*   A      = (double*)ws;     ws += (size_t)MM * DM * DM * sizeof(double);    // 512 KB
    double*   keffdT = (double*)ws;     ws += (size_t)MM * DM * KC * sizeof(double);    // 1 MB
    _Float16* keff16 = (_Float16*)ws;   ws += (size_t)MM * KC * DM * sizeof(_Float16);  // 256 KB
    int*      wl_cnt = (int*)ws;        ws += 256;                                      // 4 ctr, 64B apart
    int*      wl     = (int*)ws;        // 4 * WLC * 4 = 256 KB

    hipMemsetAsync(wl_cnt, 0, 256, stream);
    a_kernel<<<MM * DM, 128, 0, stream>>>(wk, wq, A);
    keff_kernel<<<MM * KC, 128, 0, stream>>>(cb, A, keffdT, keff16);
    argmax_mfma<<<512, 512, 0, stream>>>(latent, keff16, out, wl_cnt, wl);
    rescue_kernel<<<1024, 256, 0, stream>>>(latent, keffdT, wl_cnt, wl, out);
}